// Round 12
// baseline (186.539 us; speedup 1.0000x reference)
//
#include <hip/hip_runtime.h>
#include <hip/hip_bf16.h>

#define C   336
#define CR  84
#define BB  256
#define HW  196           // 14*14
#define NKC 11            // K chunks of 32 (K padded to 352)
#define NNF 21            // 336/16 N fragments (real)
#define NFP 24            // padded frag slots per chunk (fslot 11,22,23 = zero pad)
#define BUFS (NFP*512)    // shorts per LDS B buffer
#define NBLK 784          // gemm/norm grids: 784 blocks x 4 tiles
#define PBLK 1568         // pack grid
#define LDSW 344          // pack LDS row stride in shorts
#define TSTR 5632         // shorts per tile slot in apack (11*512)

typedef __attribute__((ext_vector_type(8))) short bf16x8;
typedef __attribute__((ext_vector_type(4))) float f32x4;

typedef __attribute__((address_space(3))) void       lds_vp;
typedef const __attribute__((address_space(1))) void gbl_vp;

__device__ __forceinline__ unsigned short f2bf(float f) {
    unsigned u = __builtin_bit_cast(unsigned, f);
    u += 0x7fffu + ((u >> 16) & 1u);   // round-to-nearest-even
    return (unsigned short)(u >> 16);
}

__device__ __forceinline__ float bf2f(unsigned short h) {
    unsigned u = (unsigned)h << 16;
    return __builtin_bit_cast(float, u);
}

__device__ __forceinline__ void gload_lds16(const void* g, void* l) {
    __builtin_amdgcn_global_load_lds((gbl_vp*)g, (lds_vp*)l, 16, 0, 0);
}

// ---------------------------------------------------------------- prep w53 -> bf16 frag-linear
// fslot 0..10 -> nf=fslot (half 0); fslot 12..21 -> nf=fslot-1 (half 1); fslot 11,22,23 = pad
__global__ void prep_w(const float* __restrict__ w53, short* __restrict__ wbf) {
    const int f = blockIdx.x;           // 0..263
    const int kc = f / NFP, fslot = f - kc * NFP;
    const int nf = (fslot < 11) ? fslot : ((fslot <= 21) ? fslot - 1 : -1);
    const int nfv = (fslot == 11 || fslot > 21) ? -1 : nf;
    const int lane = threadIdx.x;
    const int o = (nfv < 0 ? 0 : nfv) * 16 + (lane & 15);
    const int cb = kc * 32 + (lane >> 4) * 8;
    short* dst = wbf + ((size_t)f * 64 + lane) * 8;
#pragma unroll
    for (int j = 0; j < 8; ++j) {
        const int c = cb + j;
        dst[j] = (nfv >= 0 && c < C) ? (short)f2bf(w53[o * C + c]) : (short)0;
    }
}

// ---------------------------------------------------------------- SE gate: block per batch, 384 thr (proven)
__global__ void gate_kernel(const float* __restrict__ x160,
                            const float* __restrict__ w51, const float* __restrict__ b51,
                            const float* __restrict__ w52, const float* __restrict__ b52,
                            float* __restrict__ gate)
{
    __shared__ float s[C];
    __shared__ float red[C];
    __shared__ float h[CR];
    const int b = blockIdx.x, t = threadIdx.x;
    if (t < C) s[t] = x160[b * C + t];
    __syncthreads();
    if (t < C) {                       // layer 1: 84 outputs x 4 threads
        const int o = t >> 2, j = t & 3;
        float a = 0.f;
        const float* wr = w51 + o * C;
        for (int c = j; c < C; c += 4) a = fmaf(wr[c], s[c], a);
        red[t] = a;
    }
    __syncthreads();
    if (t < CR) {
        float a = red[4*t] + red[4*t+1] + red[4*t+2] + red[4*t+3] + b51[t];
        h[t] = fmaxf(a, 0.f);
    }
    __syncthreads();
    if (t < C) {                       // layer 2
        float a = b52[t];
        const float* wr = w52 + t * CR;
        for (int j = 0; j < CR; ++j) a = fmaf(wr[j], h[j], a);
        gate[b * C + t] = 1.f / (1.f + expf(-a));
    }
}

// ---------------------------------------------------------------- pack A = bf16(x159*gate), frag-linear
__global__ __launch_bounds__(128) void pack_kernel(
    const float* __restrict__ x159, const float* __restrict__ gate,
    short* __restrict__ apack)
{
    __shared__ short at[32 * LDSW];    // 22016 B
    const int tid  = threadIdx.x;
    const int lane = tid & 63;
    const int wq   = tid >> 6;         // 0..1
    const int m0   = blockIdx.x * 32;

    {   // phase 1: 64 lanes = 32 consecutive m x 2 c (coalesced)
        const int ml = lane & 31;
        const int ch = lane >> 5;
        const int m = m0 + ml;
        const int b = m / HW;
        const int p = m - b * HW;
        const float* __restrict__ xb = x159 + (size_t)b * (C * HW) + p;
        const float* __restrict__ gb = gate + b * C;
        short* row = at + ml * LDSW;
        for (int c = wq * 2 + ch; c < C; c += 4)
            row[c] = (short)f2bf(xb[(size_t)c * HW] * gb[c]);
        const int z = 336 + (wq * 2 + ch) * 2;    // zero pad cols 336..343
        row[z] = 0; row[z + 1] = 0;
    }
    __syncthreads();

    {   // phase 2: wave wq -> tile blk*2+wq, 1KB contiguous store per kc
        const int row = lane & 15;
        const int kg  = lane >> 4;
        const short* src = at + ((wq & 1) * 16 + row) * LDSW;
        short* dst = apack + (size_t)(blockIdx.x * 2 + wq) * TSTR + lane * 8;
#pragma unroll
        for (int kc = 0; kc < NKC; ++kc) {
            const int c0 = kc * 32 + kg * 8;
            bf16x8 v = {0,0,0,0,0,0,0,0};
            if (c0 < LDSW) v = *(const bf16x8*)(src + c0);   // c0==344 -> zero frag
            *(bf16x8*)(dst + (size_t)kc * 512) = v;
        }
    }
}

// ---------------------------------------------------------------- B slice staging (8 waves): 3 loads/wave
__device__ __forceinline__ void stage_slice8(const short* __restrict__ wbf,
                                             short* buf, int kc, int wid, int lane)
{
#pragma unroll
    for (int i = 0; i < 3; ++i) {
        const int fs = i * 8 + wid;    // 8 waves x 3 = 24 fslots
        gload_lds16(wbf + ((size_t)(kc * NFP + fs) * 64 + lane) * 8, buf + fs * 512);
    }
}

// ---------------------------------------------------------------- single GEMM pass, split-N in block:
// 512 thr / 8 waves; wave (h=wid>>2, tj=wid&3): tile blk*4+tj, half h (h0: nf 0..10, h1: nf 11..20).
// Rolling A prefetch 2 ahead; steady-state s_waitcnt vmcnt(4); bf16 frag store in place; stats partials.
__global__ __launch_bounds__(512, 4) void gemm_fs(
    short* __restrict__ apack,         // read tile slot, then overwrite with x166 frags
    const short* __restrict__ wbf,
    float* __restrict__ part)
{
    __shared__ short bsm[2 * BUFS];        // 49152 B (reused as float scratch after GEMM)
    const int tid  = threadIdx.x;
    const int lane = tid & 63;
    const int wid  = tid >> 6;
    const int h    = wid >> 2;             // 0..1 (N half)
    const int tj   = wid & 3;              // 0..3 (tile in block)
    const int t    = blockIdx.x * 4 + tj;
    const int F    = h ? 10 : 11;

    f32x4 acc[11];
#pragma unroll
    for (int i = 0; i < 11; ++i) acc[i] = f32x4{0.f, 0.f, 0.f, 0.f};

    const short* ap = apack + (size_t)t * TSTR + lane * 8;
    bf16x8 a[NKC];

    // prologue issue order: stage0(3), a0, a1, stage1(3) -> iter0 vmcnt(4) drains stage0+a0
    stage_slice8(wbf, bsm, 0, wid, lane);
    a[0] = *(const bf16x8*)ap;
    a[1] = *(const bf16x8*)(ap + 512);
    stage_slice8(wbf, bsm + BUFS, 1, wid, lane);

#pragma unroll
    for (int kc = 0; kc < NKC; ++kc) {
        // steady state in flight after wait: a(kc+1) + stage(kc+1) = 4 vmem ops
        if (kc == NKC - 1) asm volatile("s_waitcnt vmcnt(0)" ::: "memory");
        else               asm volatile("s_waitcnt vmcnt(4)" ::: "memory");
        __builtin_amdgcn_s_barrier();

        const short* bb = bsm + (kc & 1) * BUFS + h * (12 * 512) + lane * 8;
#pragma unroll
        for (int f = 0; f < 10; ++f) {
            const bf16x8 bfrag = *(const bf16x8*)(bb + (size_t)f * 512);
            acc[f] = __builtin_amdgcn_mfma_f32_16x16x32_bf16(a[kc], bfrag, acc[f], 0, 0, 0);
        }
        if (h == 0) {
            const bf16x8 bfrag = *(const bf16x8*)(bb + (size_t)10 * 512);
            acc[10] = __builtin_amdgcn_mfma_f32_16x16x32_bf16(a[kc], bfrag, acc[10], 0, 0, 0);
        }

        if (kc + 2 < NKC) {
            // my ds_reads retired; barrier; then a-load BEFORE stage keeps it older in queue
            asm volatile("s_waitcnt lgkmcnt(0)" ::: "memory");
            __builtin_amdgcn_s_barrier();
            a[kc + 2] = *(const bf16x8*)(ap + (size_t)(kc + 2) * 512);
            stage_slice8(wbf, bsm + (kc & 1) * BUFS, kc + 2, wid, lane);
        }
    }
    __syncthreads();   // full drain (all waves' A-reads + ds done) before in-place write / LDS reuse

    // ---- store x166 as bf16, fragment-linear, over this tile's own apack slot (halves disjoint)
    unsigned short* xp = (unsigned short*)apack + (size_t)t * TSTR + lane * 4;
#pragma unroll
    for (int f = 0; f < 11; ++f) {
        if (f >= F) break;
        const int nf = h * 11 + f;
        uint2 d;
        d.x = (unsigned)f2bf(acc[f][0]) | ((unsigned)f2bf(acc[f][1]) << 16);
        d.y = (unsigned)f2bf(acc[f][2]) | ((unsigned)f2bf(acc[f][3]) << 16);
        *(uint2*)(xp + (size_t)nf * 256) = d;   // 64 lanes x 8B = 512B contiguous
    }

    // ---- per-block channel partials (exact f32)
    float* lds_s = (float*)bsm;            // [8][336]
    float* lds_q = lds_s + 8 * C;          // [8][336] (21504 B < 49152)
#pragma unroll
    for (int f = 0; f < 11; ++f) {
        if (f >= F) break;
        const int nf = h * 11 + f;
        float s = acc[f][0] + acc[f][1] + acc[f][2] + acc[f][3];
        float q = acc[f][0]*acc[f][0] + acc[f][1]*acc[f][1]
                + acc[f][2]*acc[f][2] + acc[f][3]*acc[f][3];
        s += __shfl_xor(s, 16); q += __shfl_xor(q, 16);
        s += __shfl_xor(s, 32); q += __shfl_xor(q, 32);
        if (lane < 16) { lds_s[wid * C + nf*16 + lane] = s; lds_q[wid * C + nf*16 + lane] = q; }
    }
    __syncthreads();
    for (int i = tid; i < C; i += 512) {
        const int wb = (i < 176) ? 0 : 4;  // half0 channels from waves 0..3, half1 from 4..7
        float s = lds_s[wb*C + i] + lds_s[(wb+1)*C + i] + lds_s[(wb+2)*C + i] + lds_s[(wb+3)*C + i];
        float q = lds_q[wb*C + i] + lds_q[(wb+1)*C + i] + lds_q[(wb+2)*C + i] + lds_q[(wb+3)*C + i];
        part[(size_t)blockIdx.x * (2*C) + 2*i]     = s;
        part[(size_t)blockIdx.x * (2*C) + 2*i + 1] = q;
    }
}

// ---------------------------------------------------------------- fold partials -> per-channel (a,b)
__global__ void stats_final_a(const float* __restrict__ part,
                              const float* __restrict__ gamma, const float* __restrict__ beta,
                              float* __restrict__ ab)
{
    const int o = blockIdx.x;          // 0..335
    const int lane = threadIdx.x;      // 0..63
    float s = 0.f, q = 0.f;
    for (int i = lane; i < NBLK; i += 64) {
        s += part[(size_t)i * (2*C) + 2*o];
        q += part[(size_t)i * (2*C) + 2*o + 1];
    }
#pragma unroll
    for (int d = 1; d < 64; d <<= 1) { s += __shfl_xor(s, d); q += __shfl_xor(q, d); }
    if (lane == 0) {
        const float invN = 1.f / (float)(BB * HW);
        const float mean = s * invN;
        const float var  = fmaxf(q * invN - mean * mean, 0.f);
        const float rstd = rsqrtf(var + 1e-5f);
        const float a = rstd * gamma[o];
        ab[2*o]     = a;
        ab[2*o + 1] = beta[o] - mean * a;
    }
}

// ---------------------------------------------------------------- norm + transpose: frag bf16 -> out f32 (proven)
__global__ __launch_bounds__(256) void norm_t(
    const short* __restrict__ apack,   // x166 frag blob (tile-slot stride TSTR)
    const float* __restrict__ ab, float* __restrict__ out)
{
    __shared__ unsigned short xs[4 * NNF * 256];   // 21504 shorts = 43008 B
    __shared__ float s_ab[2 * C];
    const int tid  = threadIdx.x;
    const int lane = tid & 63;
    const int wid  = tid >> 6;
    const int T0   = blockIdx.x * 4;

    // stage: 42 wave-calls x 1KB; per-lane global src handles tile-slot stride
    const unsigned short* src = (const unsigned short*)apack;
    for (int s = wid; s < 42; s += 4) {
        const int u    = s * 64 + lane;        // 16B unit, 672 per tile
        const int tile = u / 672;
        const int win  = u - tile * 672;
        gload_lds16(src + (size_t)(T0 + tile) * TSTR + (size_t)win * 8,
                    (unsigned short*)xs + (size_t)s * 512);
    }
    for (int i = tid; i < 2 * C; i += 256) s_ab[i] = ab[i];
    __syncthreads();                           // drains vmcnt+lgkm

    // transpose-read + normalize + store
    const int o_sub = lane >> 4;               // 0..3
    const int q     = lane & 15;               // m-quad index
    const int tl    = q >> 2;
    const int qq    = q & 3;
    const int r     = wid * 4 + o_sub;         // 0..15
    const int m     = blockIdx.x * 64 + q * 4;
    const int bC    = m / HW;
    const int pC    = m - bC * HW;
    float* __restrict__ ob = out + (size_t)bC * (C * HW) + pC;

#pragma unroll
    for (int i = 0; i < NNF; ++i) {
        const int o = i * 16 + r;
        const unsigned short* pp = xs + (size_t)tl * (NNF*256) + (size_t)i * 256
                                      + (size_t)(qq * 16 + r) * 4;
        const uint2 d = *(const uint2*)pp;
        const float a  = s_ab[2*o];
        const float b2 = s_ab[2*o + 1];
        f32x4 v;
        v[0] = fmaf(bf2f((unsigned short)(d.x & 0xffff)), a, b2);
        v[1] = fmaf(bf2f((unsigned short)(d.x >> 16)),    a, b2);
        v[2] = fmaf(bf2f((unsigned short)(d.y & 0xffff)), a, b2);
        v[3] = fmaf(bf2f((unsigned short)(d.y >> 16)),    a, b2);
        *(f32x4*)(ob + (size_t)o * HW) = v;    // 16 q-lanes -> 256B contiguous
    }
}

// ---------------------------------------------------------------- launch
extern "C" void kernel_launch(void* const* d_in, const int* in_sizes, int n_in,
                              void* d_out, int out_size, void* d_ws, size_t ws_size,
                              hipStream_t stream)
{
    const float* x160  = (const float*)d_in[0];
    const float* x159  = (const float*)d_in[1];
    const float* w51   = (const float*)d_in[2];
    const float* b51   = (const float*)d_in[3];
    const float* w52   = (const float*)d_in[4];
    const float* b52   = (const float*)d_in[5];
    const float* w53   = (const float*)d_in[6];
    const float* gamma = (const float*)d_in[7];
    const float* beta  = (const float*)d_in[8];
    float* out = (float*)d_out;

    // ws layout (37.7 MB, proven to fit; gate aliases part — dead before part is written)
    char* ws = (char*)d_ws;
    short* wbf   = (short*)ws;                   // 270,336 B
    float* ab    = (float*)(ws + 270336);        //   2,688 -> 273,024
    float* part  = (float*)(ws + 273024);        // 784*672*4 = 2,107,392 -> 2,380,416
    float* gate  = (float*)(ws + 273024);        // 344,064 B (alias over part)
    short* apack = (short*)(ws + 2380416);       // 3136*5632*2 = 35,323,904 -> 37,704,320

    hipLaunchKernelGGL(prep_w,        dim3(11*NFP), dim3(64),  0, stream, w53, wbf);
    hipLaunchKernelGGL(gate_kernel,   dim3(BB),     dim3(384), 0, stream, x160, w51, b51, w52, b52, gate);
    hipLaunchKernelGGL(pack_kernel,   dim3(PBLK),   dim3(128), 0, stream, x159, gate, apack);
    hipLaunchKernelGGL(gemm_fs,       dim3(NBLK),   dim3(512), 0, stream, apack, wbf, part);
    hipLaunchKernelGGL(stats_final_a, dim3(C),      dim3(64),  0, stream, part, gamma, beta, ab);
    hipLaunchKernelGGL(norm_t,        dim3(NBLK),   dim3(256), 0, stream, apack, ab, out);
}